// Round 11
// baseline (715.630 us; speedup 1.0000x reference)
//
#include <hip/hip_runtime.h>
#include <math.h>

#define NB   4
#define NG0  2500
#define ETOT 100000
#define CH   512
#define NEGS 0.2f
#define BCAP 64   // bucket capacity per dst node (max in-degree ~25)

static const int h_Ns[5]  = {10000, 7000, 4900, 3432, 2404};
static const int h_ngs[4] = {2500, 1750, 1225, 858};
static const int h_ks[4]  = {1750, 1225, 858, 601};

typedef __bf16 bf16x8 __attribute__((ext_vector_type(8)));
typedef __bf16 bf16x4 __attribute__((ext_vector_type(4)));
typedef float  f32x4  __attribute__((ext_vector_type(4)));

#define GLOAD16(g, l)                                                              \
    __builtin_amdgcn_global_load_lds(                                              \
        (const __attribute__((address_space(1))) unsigned int*)(g),                \
        (__attribute__((address_space(3))) unsigned int*)(l), 16, 0, 0)

// ---------------- layer-0: edge init + bucket-CSR build ----------------
__global__ void k_init_build(const int* __restrict__ ei, int* src, int* dst, int* mask,
                             int* cnt, int* bucket) {
    int e = blockIdx.x * blockDim.x + threadIdx.x;
    if (e >= ETOT) return;
    int s = ei[e], d = ei[ETOT + e];
    src[e] = s; dst[e] = d; mask[e] = 1;
    int p = atomicAdd(&cnt[d], 1);
    if (p < BCAP) bucket[(d << 6) + p] = s;
}

// ---------------- layer>0: remap + bucket-CSR build fused ----------------
__global__ void k_remap_build(int* src, int* dst, int* mask, const int* __restrict__ newidx,
                              int* cnt, int* bucket) {
    int e = blockIdx.x * blockDim.x + threadIdx.x;
    if (e >= ETOT) return;
    if (!mask[e]) return;
    int ns = newidx[src[e]];
    int nd = newidx[dst[e]];
    if (ns >= 0 && nd >= 0) {
        src[e] = ns; dst[e] = nd;
        int p = atomicAdd(&cnt[nd], 1);
        if (p < BCAP) bucket[(nd << 6) + p] = ns;
    } else mask[e] = 0;
}

// ---------------- f32 -> bf16 hi/lo split (layer 0 only) ----------------
__global__ void k_cvtA(const float* __restrict__ x, __bf16* __restrict__ hi,
                       __bf16* __restrict__ lo, int n) {
    int i = (blockIdx.x * blockDim.x + threadIdx.x) * 8;
    if (i >= n) return;
    float4 a = *(const float4*)(x + i);
    float4 b = *(const float4*)(x + i + 4);
    float f[8] = {a.x, a.y, a.z, a.w, b.x, b.y, b.z, b.w};
    bf16x8 vh, vl;
#pragma unroll
    for (int j = 0; j < 8; ++j) {
        __bf16 h = (__bf16)f[j];
        vh[j] = h;
        vl[j] = (__bf16)(f[j] - (float)h);
    }
    *(bf16x8*)(hi + i) = vh;
    *(bf16x8*)(lo + i) = vl;
}

// ---------------- W transpose + split ----------------
__global__ void k_cvtWt(const float* __restrict__ gWl, const float* __restrict__ gWr,
                        __bf16* __restrict__ WtH, __bf16* __restrict__ WtL) {
    int m = blockIdx.z;
    const float* src = ((m & 1) ? gWr : gWl) + (size_t)(m >> 1) * 512 * 1024;
    __bf16* oh = WtH + (size_t)m * 1024 * 512;
    __bf16* ol = WtL + (size_t)m * 1024 * 512;
    int nb = blockIdx.x * 32, kb = blockIdx.y * 32;
    __shared__ float tile[32][33];
#pragma unroll
    for (int j = 0; j < 4; ++j) {
        int kk = threadIdx.y + j * 8;
        tile[kk][threadIdx.x] = src[(size_t)(kb + kk) * 1024 + nb + threadIdx.x];
    }
    __syncthreads();
#pragma unroll
    for (int j = 0; j < 4; ++j) {
        int nn = threadIdx.y + j * 8;
        float v = tile[threadIdx.x][nn];
        __bf16 h = (__bf16)v;
        __bf16 l = (__bf16)(v - (float)h);
        oh[(size_t)(nb + nn) * 512 + kb + threadIdx.x] = h;
        ol[(size_t)(nb + nn) * 512 + kb + threadIdx.x] = l;
    }
}

// ---------------- generic f32 transpose ----------------
__global__ void k_transpose(const float* __restrict__ src, float* __restrict__ dst, int R, int C) {
    __shared__ float tile[32][33];
    int rb = blockIdx.y * 32, cb = blockIdx.x * 32;
#pragma unroll
    for (int j = 0; j < 4; ++j) {
        int r = rb + threadIdx.y + j * 8;
        int c = cb + threadIdx.x;
        if (r < R && c < C) tile[threadIdx.y + j * 8][threadIdx.x] = src[(size_t)r * C + c];
    }
    __syncthreads();
#pragma unroll
    for (int j = 0; j < 4; ++j) {
        int c = cb + threadIdx.y + j * 8;
        int r = rb + threadIdx.x;
        if (r < R && c < C) dst[(size_t)c * R + r] = tile[threadIdx.x][threadIdx.y + j * 8];
    }
}

// ---------------- combined bias [4][2048] = [bl | br] ----------------
__global__ void k_prep_bias(const float* __restrict__ gbl, const float* __restrict__ gbr,
                            float* __restrict__ biasC) {
    int i = blockIdx.x * blockDim.x + threadIdx.x;
    if (i >= 4 * 2048) return;
    int l = i >> 11, c = i & 2047;
    biasC[i] = (c < 1024) ? gbl[l * 1024 + c] : gbr[l * 1024 + c - 1024];
}

// ---------------- bf16x3 MFMA GEMM (R6 best-measured variant) ----------------
__global__ __launch_bounds__(256) void k_gemm3(const __bf16* __restrict__ Ah, const __bf16* __restrict__ Al,
                                               const __bf16* __restrict__ Bh, const __bf16* __restrict__ Bl,
                                               const float* __restrict__ bias, float* __restrict__ out,
                                               int M, int ldo) {
    __shared__ __bf16 sAh[128 * 32];
    __shared__ __bf16 sAl[128 * 32];
    __shared__ __bf16 sBh[128 * 32];
    __shared__ __bf16 sBl[128 * 32];
    int tid = threadIdx.x;
    int nRows = (M + 127) >> 7;
    int pid = blockIdx.x;
    int fullG = nRows >> 3;
    int inFull = fullG << 7;
    int rowT, colT;
    if (pid < inFull) {
        int g = pid >> 7, r = pid & 127;
        rowT = (g << 3) + (r & 7);
        colT = r >> 3;
    } else {
        int r = pid - inFull;
        int tail = nRows - (fullG << 3);
        rowT = (fullG << 3) + r % tail;
        colT = r / tail;
    }
    int rowBase = rowT << 7, colBase = colT << 7;
    int wave = tid >> 6, lane = tid & 63;
    int wr = (wave >> 1) * 64, wc = (wave & 1) * 64;
    f32x4 acc[4][4];
#pragma unroll
    for (int a = 0; a < 4; ++a)
#pragma unroll
        for (int b = 0; b < 4; ++b) { acc[a][b][0] = 0.f; acc[a][b][1] = 0.f; acc[a][b][2] = 0.f; acc[a][b][3] = 0.f; }

    int srow0 = tid >> 2;
    int ps = tid & 3;
    auto stage = [&](int k0) {
#pragma unroll
        for (int c = 0; c < 2; ++c) {
            int row = (c << 6) + srow0;
            int ls = ps ^ ((row >> 1) & 3);
            int ldsoff = c * 2048 + tid * 8;
            int grA = rowBase + row; if (grA >= M) grA = M - 1;
            int gnB = colBase + row;
            const __bf16* gah = Ah + (size_t)grA * 512 + k0 + ls * 8;
            const __bf16* gal = Al + (size_t)grA * 512 + k0 + ls * 8;
            const __bf16* gbh = Bh + (size_t)gnB * 512 + k0 + ls * 8;
            const __bf16* gbl2 = Bl + (size_t)gnB * 512 + k0 + ls * 8;
            GLOAD16(gah, &sAh[ldsoff]);
            GLOAD16(gal, &sAl[ldsoff]);
            GLOAD16(gbh, &sBh[ldsoff]);
            GLOAD16(gbl2, &sBl[ldsoff]);
        }
    };

    int fl = lane & 15, g = lane >> 4;
    stage(0);
    __syncthreads();
    for (int ks = 0; ks < 16; ++ks) {
        bf16x8 afh[4], afl[4], bfh[4], bfl[4];
#pragma unroll
        for (int fr = 0; fr < 4; ++fr) {
            int r = wr + fr * 16 + fl;
            int po = (g ^ ((r >> 1) & 3)) << 3;
            afh[fr] = *(const bf16x8*)&sAh[r * 32 + po];
            afl[fr] = *(const bf16x8*)&sAl[r * 32 + po];
        }
#pragma unroll
        for (int fc = 0; fc < 4; ++fc) {
            int cc = wc + fc * 16 + fl;
            int po = (g ^ ((cc >> 1) & 3)) << 3;
            bfh[fc] = *(const bf16x8*)&sBh[cc * 32 + po];
            bfl[fc] = *(const bf16x8*)&sBl[cc * 32 + po];
        }
        __syncthreads();
        if (ks < 15) stage((ks + 1) * 32);
#pragma unroll
        for (int fr = 0; fr < 4; ++fr) {
#pragma unroll
            for (int fc = 0; fc < 4; ++fc) {
                acc[fr][fc] = __builtin_amdgcn_mfma_f32_16x16x32_bf16(afh[fr], bfh[fc], acc[fr][fc], 0, 0, 0);
                acc[fr][fc] = __builtin_amdgcn_mfma_f32_16x16x32_bf16(afh[fr], bfl[fc], acc[fr][fc], 0, 0, 0);
                acc[fr][fc] = __builtin_amdgcn_mfma_f32_16x16x32_bf16(afl[fr], bfh[fc], acc[fr][fc], 0, 0, 0);
            }
        }
        __syncthreads();
    }
    int orow0 = rowBase + wr + 4 * (lane >> 4);
    int ocol0 = colBase + wc + fl;
#pragma unroll
    for (int fr = 0; fr < 4; ++fr) {
#pragma unroll
        for (int fc = 0; fc < 4; ++fc) {
            int col = ocol0 + fc * 16;
            float bv = bias[col];
#pragma unroll
            for (int j = 0; j < 4; ++j) {
                int row = orow0 + fr * 16 + j;
                if (row < M) out[(size_t)row * ldo + col] = acc[fr][fc][j] + bv;
            }
        }
    }
}

// ---------------- per-row logit + row load helper ----------------
__device__ __forceinline__ float gat_row(const float* __restrict__ xsp,
                                         const float* xr, const float* at, float* v) {
    float p = 0.f;
#pragma unroll
    for (int j = 0; j < 16; j += 4) {
        float4 vv = *(const float4*)(xsp + j);
        v[j + 0] = vv.x; v[j + 1] = vv.y; v[j + 2] = vv.z; v[j + 3] = vv.w;
    }
#pragma unroll
    for (int j = 0; j < 16; ++j) {
        float e = v[j] + xr[j];
        e = e > 0.f ? e : NEGS * e;
        p += e * at[j];
    }
    return p;
}

// ---------------- fused GAT: wave per dst node, 2-edge unrolled online softmax ----------------
__global__ __launch_bounds__(256) void k_gat_wave(const float* __restrict__ xlr,
                                                  const int* __restrict__ cnt,
                                                  const int* __restrict__ bucket,
                                                  const float* __restrict__ att,
                                                  const float* __restrict__ bias,
                                                  const float* __restrict__ Wrel,
                                                  const float* __restrict__ Wroot,
                                                  float* __restrict__ out,
                                                  float* __restrict__ y0, float* __restrict__ y1, int N) {
    int d = (blockIdx.x * blockDim.x + threadIdx.x) >> 6;
    if (d >= N) return;
    int lane = threadIdx.x & 63;
    int c0 = lane * 16;
    float xr[16], at[16];
#pragma unroll
    for (int j = 0; j < 16; j += 4) {
        float4 a = *(const float4*)(xlr + (size_t)d * 2048 + 1024 + c0 + j);
        xr[j + 0] = a.x; xr[j + 1] = a.y; xr[j + 2] = a.z; xr[j + 3] = a.w;
        float4 b = *(const float4*)(att + c0 + j);
        at[j + 0] = b.x; at[j + 1] = b.y; at[j + 2] = b.z; at[j + 3] = b.w;
    }
    float acc[16], m, den;
    {
        float v[16];
        float p = gat_row(xlr + (size_t)d * 2048 + c0, xr, at, v);
#pragma unroll
        for (int o = 1; o <= 16; o <<= 1) p += __shfl_xor(p, o, 64);
        m = p; den = 1.f;
#pragma unroll
        for (int j = 0; j < 16; ++j) acc[j] = v[j];
    }
    int rs = d << 6;
    int re = rs + cnt[d];
    int e = rs;
    for (; e + 1 < re; e += 2) {
        int s1 = bucket[e], s2 = bucket[e + 1];
        float v1[16], v2[16];
        float p1 = gat_row(xlr + (size_t)s1 * 2048 + c0, xr, at, v1);
        float p2 = gat_row(xlr + (size_t)s2 * 2048 + c0, xr, at, v2);
#pragma unroll
        for (int o = 1; o <= 16; o <<= 1) {
            p1 += __shfl_xor(p1, o, 64);
            p2 += __shfl_xor(p2, o, 64);
        }
        float nm = fmaxf(m, fmaxf(p1, p2));
        float sc = __expf(m - nm);
        float w1 = __expf(p1 - nm);
        float w2 = __expf(p2 - nm);
        m = nm;
        den = den * sc + w1 + w2;
#pragma unroll
        for (int j = 0; j < 16; ++j) acc[j] = (acc[j] * sc + w1 * v1[j]) + w2 * v2[j];
    }
    if (e < re) {
        int s1 = bucket[e];
        float v1[16];
        float p1 = gat_row(xlr + (size_t)s1 * 2048 + c0, xr, at, v1);
#pragma unroll
        for (int o = 1; o <= 16; o <<= 1) p1 += __shfl_xor(p1, o, 64);
        float nm = fmaxf(m, p1);
        float sc = __expf(m - nm);
        float w1 = __expf(p1 - nm);
        m = nm;
        den = den * sc + w1;
#pragma unroll
        for (int j = 0; j < 16; ++j) acc[j] = acc[j] * sc + w1 * v1[j];
    }
    float inv = 1.f / fmaxf(den, 1e-16f);
    float o16[16];
#pragma unroll
    for (int j = 0; j < 16; ++j) {
        float a = acc[j] * inv;
        float b = __shfl_xor(a, 32, 64);
        o16[j] = 0.5f * (a + b);
    }
    float s0 = 0.f, s1v = 0.f;
    if (lane < 32) {
        const float* bp = bias + c0;
        const float* wa = Wrel + c0;
        const float* wb = Wroot + c0;
        float* op = out + (size_t)d * 512 + c0;
#pragma unroll
        for (int j = 0; j < 16; j += 4) {
            float4 bb = *(const float4*)(bp + j);
            float4 va = *(const float4*)(wa + j);
            float4 vb = *(const float4*)(wb + j);
            float4 r;
            r.x = fmaxf(o16[j + 0] + bb.x, 0.f);
            r.y = fmaxf(o16[j + 1] + bb.y, 0.f);
            r.z = fmaxf(o16[j + 2] + bb.z, 0.f);
            r.w = fmaxf(o16[j + 3] + bb.w, 0.f);
            *(float4*)(op + j) = r;
            s0 += r.x * va.x + r.y * va.y + r.z * va.z + r.w * va.w;
            s1v += r.x * vb.x + r.y * vb.y + r.z * vb.z + r.w * vb.w;
        }
    }
#pragma unroll
    for (int o = 16; o > 0; o >>= 1) {
        s0 += __shfl_xor(s0, o, 64);
        s1v += __shfl_xor(s1v, o, 64);
    }
    s0 += __shfl_xor(s0, 32, 64);
    s1v += __shfl_xor(s1v, 32, 64);
    if (lane == 0) { y0[d] = s0; y1[d] = s1v; }
}

// ---------------- fused SAG score + per-graph top-k radix select ----------------
__global__ __launch_bounds__(256) void k_topk_score(const float* __restrict__ y0, const float* __restrict__ y1,
                                                    const int* __restrict__ cnt, const int* __restrict__ bucket,
                                                    const float* __restrict__ brel_p, int ng, int k,
                                                    int* __restrict__ newidx, int* __restrict__ sel_old,
                                                    float* __restrict__ sel_scale) {
    int b = blockIdx.x;
    int t = threadIdx.x;
    int lane = t & 63, wave = t >> 6;
    __shared__ unsigned int keys[NG0];
    __shared__ float sval[NG0];
    __shared__ int hist[256];
    __shared__ int scnt[256];
    __shared__ int wsum4[4];
    __shared__ unsigned int s_pref, s_amask;
    __shared__ int s_krem, s_gt;
    float brel = brel_p[0];
    for (int i = t; i < ng; i += 256) {
        int d = b * ng + i;
        float s = y1[d] + brel;
        int rs = d << 6, re = rs + cnt[d];
        for (int e = rs; e < re; ++e) s += y0[bucket[e]];
        sval[i] = s;
        unsigned int u = __float_as_uint(s);
        u = (u & 0x80000000u) ? ~u : (u | 0x80000000u);
        keys[i] = u;
        newidx[d] = -1;
    }
    if (t == 0) { s_pref = 0u; s_amask = 0u; s_krem = k; s_gt = 0; }
    __syncthreads();
    for (int pass = 0; pass < 4; ++pass) {
        int shift = 24 - 8 * pass;
        hist[t] = 0;
        __syncthreads();
        unsigned int amask = s_amask, pref = s_pref;
        int krem_c = s_krem;
        for (int i = t; i < ng; i += 256) {
            unsigned int u = keys[i];
            if ((u & amask) == pref) atomicAdd(&hist[(u >> shift) & 255], 1);
        }
        __syncthreads();
        int rh = hist[255 - t];
        int x = rh;
#pragma unroll
        for (int o = 1; o < 64; o <<= 1) {
            int y = __shfl_up(x, o, 64);
            if (lane >= o) x += y;
        }
        if (lane == 63) wsum4[wave] = x;
        __syncthreads();
        int woff = 0;
#pragma unroll
        for (int wv = 0; wv < 3; ++wv) if (wave > wv) woff += wsum4[wv];
        x += woff;
        if (x >= krem_c && (x - rh) < krem_c) {
            s_pref = pref | ((unsigned int)(255 - t) << shift);
            s_amask = amask | (0xFFu << shift);
            s_krem = krem_c - (x - rh);
        }
        __syncthreads();
    }
    unsigned int T = s_pref;
    int krem = s_krem;
    int chunk = (ng + 255) / 256;
    int lo = t * chunk, hi = min(ng, lo + chunk);
    int ceq = 0;
    for (int i = lo; i < hi; ++i) if (keys[i] == T) ceq++;
    scnt[t] = ceq;
    __syncthreads();
    for (int o = 1; o < 256; o <<= 1) {
        int add = (t >= o) ? scnt[t - o] : 0;
        __syncthreads();
        scnt[t] += add;
        __syncthreads();
    }
    int eq_rank = scnt[t] - ceq;
    for (int i = lo; i < hi; ++i) {
        unsigned int u = keys[i];
        int slot = -1;
        if (u > T) slot = atomicAdd(&s_gt, 1);
        else if (u == T) {
            if (eq_rank < krem) slot = (k - krem) + eq_rank;
            eq_rank++;
        }
        if (slot >= 0) {
            int oldg = b * ng + i;
            int newg = b * k + slot;
            newidx[oldg] = newg;
            sel_old[newg] = oldg;
            sel_scale[newg] = tanhf(sval[i]);
        }
    }
}

// ---------------- fused pool (bf16 split + cnt zero) & readout phase 1 ----------------
__global__ __launch_bounds__(256) void k_pool_readout(const float* __restrict__ gatout,
                                                      const int* __restrict__ sel_old,
                                                      const float* __restrict__ sel_scale,
                                                      __bf16* __restrict__ hi, __bf16* __restrict__ lo,
                                                      int* __restrict__ cnt, int k,
                                                      float* __restrict__ pmax, float* __restrict__ psum) {
    int npoolb = (NB * k) >> 1;
    int bid = blockIdx.x;
    if (bid < npoolb) {
        int nn = (bid << 1) + (threadIdx.x >> 7);
        int t2 = threadIdx.x & 127;
        if (t2 == 0) cnt[nn] = 0;
        int so = sel_old[nn];
        float sc = sel_scale[nn];
        int c = t2 * 4;
        float4 vv = *(const float4*)(gatout + (size_t)so * 512 + c);
        vv.x *= sc; vv.y *= sc; vv.z *= sc; vv.w *= sc;
        float f[4] = {vv.x, vv.y, vv.z, vv.w};
        bf16x4 vh, vl;
#pragma unroll
        for (int j = 0; j < 4; ++j) {
            __bf16 hh = (__bf16)f[j];
            vh[j] = hh;
            vl[j] = (__bf16)(f[j] - (float)hh);
        }
        *(bf16x4*)(hi + (size_t)nn * 512 + c) = vh;
        *(bf16x4*)(lo + (size_t)nn * 512 + c) = vl;
        return;
    }
    int rb = bid - npoolb;          // 0..63
    int b = rb >> 4;
    int cg = (rb >> 3) & 1;
    int rc = rb & 7;
    int t = threadIdx.x;
    int c4 = t & 63;
    int rl = t >> 6;
    int col = cg * 256 + c4 * 4;
    int rstart = rc * 4 + rl;
    float4 mx = make_float4(-1e30f, -1e30f, -1e30f, -1e30f);
    float4 sm = make_float4(0.f, 0.f, 0.f, 0.f);
    for (int j = rstart; j < k; j += 32) {
        int so = sel_old[b * k + j];
        float sc = sel_scale[b * k + j];
        float4 v = *(const float4*)(gatout + (size_t)so * 512 + col);
        v.x *= sc; v.y *= sc; v.z *= sc; v.w *= sc;
        mx.x = fmaxf(mx.x, v.x); mx.y = fmaxf(mx.y, v.y); mx.z = fmaxf(mx.z, v.z); mx.w = fmaxf(mx.w, v.w);
        sm.x += v.x; sm.y += v.y; sm.z += v.z; sm.w += v.w;
    }
    __shared__ float lmx[256 * 4];
    __shared__ float lsm[256 * 4];
    int li = c4 * 4 + rl * 256;
    lmx[li + 0] = mx.x; lmx[li + 1] = mx.y; lmx[li + 2] = mx.z; lmx[li + 3] = mx.w;
    lsm[li + 0] = sm.x; lsm[li + 1] = sm.y; lsm[li + 2] = sm.z; lsm[li + 3] = sm.w;
    __syncthreads();
    if (rl == 0) {
        int ci = c4 * 4;
#pragma unroll
        for (int q = 0; q < 4; ++q) {
            float m = fmaxf(fmaxf(lmx[ci + q], lmx[ci + q + 256]), fmaxf(lmx[ci + q + 512], lmx[ci + q + 768]));
            float s = lsm[ci + q] + lsm[ci + q + 256] + lsm[ci + q + 512] + lsm[ci + q + 768];
            size_t o = ((size_t)(b * 8 + rc)) * 512 + col + q;
            pmax[o] = m;
            psum[o] = s;
        }
    }
}

// ---------------- readout final: fold 4 layers x 8 chunks once ----------------
__global__ __launch_bounds__(512) void k_readout_fin_all(const float* __restrict__ pmax,
                                                         const float* __restrict__ psum,
                                                         float* __restrict__ readout) {
    const int ks[4] = {1750, 1225, 858, 601};
    int b = blockIdx.x;
    int c = threadIdx.x;
    float accm = 0.f, accs = 0.f;
#pragma unroll
    for (int L = 0; L < 4; ++L) {
        float m = -1e30f, s = 0.f;
#pragma unroll
        for (int rc = 0; rc < 8; ++rc) {
            size_t o = ((size_t)(L * NB * 8) + b * 8 + rc) * 512 + c;
            m = fmaxf(m, pmax[o]);
            s += psum[o];
        }
        accm += m;
        accs += s / (float)ks[L];
    }
    readout[b * 1024 + c] = accm;
    readout[b * 1024 + 512 + c] = accs;
}

// ---------------- MLP stages ----------------
__global__ __launch_bounds__(256) void k_mlp1(const float* __restrict__ readout, const float* __restrict__ W1t,
                                              const float* __restrict__ b1, float* __restrict__ h1) {
    int wid = (blockIdx.x * blockDim.x + threadIdx.x) >> 6;
    int lane = threadIdx.x & 63;
    int b = wid >> 9, col = wid & 511;
    const float* rp = readout + b * 1024 + lane * 16;
    const float* wp = W1t + (size_t)col * 1024 + lane * 16;
    float s = 0.f;
#pragma unroll
    for (int j = 0; j < 4; ++j) {
        float4 v = *(const float4*)(rp + j * 4);
        float4 w = *(const float4*)(wp + j * 4);
        s += v.x * w.x + v.y * w.y + v.z * w.z + v.w * w.w;
    }
#pragma unroll
    for (int o = 32; o > 0; o >>= 1) s += __shfl_xor(s, o, 64);
    if (lane == 0) h1[b * 512 + col] = fmaxf(s + b1[col], 0.f);
}

__global__ __launch_bounds__(256) void k_mlp2(const float* __restrict__ h1, const float* __restrict__ W2t,
                                              const float* __restrict__ b2, float* __restrict__ h2) {
    int wid = (blockIdx.x * blockDim.x + threadIdx.x) >> 6;
    int lane = threadIdx.x & 63;
    int b = wid >> 8, col = wid & 255;
    const float* hp = h1 + b * 512 + lane * 8;
    const float* wp = W2t + (size_t)col * 512 + lane * 8;
    float s = 0.f;
#pragma unroll
    for (int j = 0; j < 2; ++j) {
        float4 v = *(const float4*)(hp + j * 4);
        float4 w = *(const float4*)(wp + j * 4);
        s += v.x * w.x + v.y * w.y + v.z * w.z + v.w * w.w;
    }
#pragma unroll
    for (int o = 32; o > 0; o >>= 1) s += __shfl_xor(s, o, 64);
    if (lane == 0) h2[b * 256 + col] = fmaxf(s + b2[col], 0.f);
}

__global__ __launch_bounds__(256) void k_mlp3(const float* __restrict__ h2, const float* __restrict__ W3,
                                              const float* __restrict__ b3, float* __restrict__ out) {
    int b = threadIdx.x >> 6;
    int lane = threadIdx.x & 63;
    float hv[4];
    int idx[4];
#pragma unroll
    for (int j = 0; j < 4; ++j) { idx[j] = lane + j * 64; hv[j] = h2[b * 256 + idx[j]]; }
    float lg[5];
#pragma unroll
    for (int q = 0; q < 5; ++q) {
        float p = 0.f;
#pragma unroll
        for (int j = 0; j < 4; ++j) p += hv[j] * W3[idx[j] * 5 + q];
#pragma unroll
        for (int o = 32; o > 0; o >>= 1) p += __shfl_xor(p, o, 64);
        lg[q] = p + b3[q];
    }
    if (lane == 0) {
        float m = lg[0];
#pragma unroll
        for (int q = 1; q < 5; ++q) m = fmaxf(m, lg[q]);
        float den = 0.f;
#pragma unroll
        for (int q = 0; q < 5; ++q) den += __expf(lg[q] - m);
#pragma unroll
        for (int q = 0; q < 5; ++q) {
            out[b * 5 + q] = lg[q];
            out[NB * 5 + b * 5 + q] = __expf(lg[q] - m) / den;
        }
    }
}

extern "C" void kernel_launch(void* const* d_in, const int* in_sizes, int n_in,
                              void* d_out, int out_size, void* d_ws, size_t ws_size,
                              hipStream_t stream) {
    const float* x0    = (const float*)d_in[0];
    const int*   ei    = (const int*)d_in[1];
    const float* gWl   = (const float*)d_in[2];
    const float* gbl   = (const float*)d_in[3];
    const float* gWr   = (const float*)d_in[4];
    const float* gbr   = (const float*)d_in[5];
    const float* gatt  = (const float*)d_in[6];
    const float* gbias = (const float*)d_in[7];
    const float* sWrel = (const float*)d_in[8];
    const float* sbrel = (const float*)d_in[9];
    const float* sWroot= (const float*)d_in[10];
    const float* W1 = (const float*)d_in[11];
    const float* b1 = (const float*)d_in[12];
    const float* W2 = (const float*)d_in[13];
    const float* b2 = (const float*)d_in[14];
    const float* W3 = (const float*)d_in[15];
    const float* b3 = (const float*)d_in[16];
    float* out = (float*)d_out;

    char* base = (char*)d_ws;
    size_t off = 0;
    auto alloc = [&](size_t bytes) -> void* {
        void* p = base + off;
        off += (bytes + 255) & ~(size_t)255;
        return p;
    };
    int*   s_src   = (int*)alloc((size_t)ETOT * 4);
    int*   s_dst   = (int*)alloc((size_t)ETOT * 4);
    int*   s_mask  = (int*)alloc((size_t)ETOT * 4);
    int*   bucket  = (int*)alloc((size_t)h_Ns[0] * BCAP * 4);
    int*   cnt     = (int*)alloc((size_t)(h_Ns[0] + 1) * 4);
    int*   newidx  = (int*)alloc((size_t)h_Ns[0] * 4);
    int*   sel_old = (int*)alloc((size_t)7000 * 4);
    float* sel_scale = (float*)alloc((size_t)7000 * 4);
    float* readout = (float*)alloc((size_t)NB * 1024 * 4);
    float* pmax    = (float*)alloc((size_t)4 * NB * 8 * 512 * 4);
    float* psum    = (float*)alloc((size_t)4 * NB * 8 * 512 * 4);
    float* y0      = (float*)alloc((size_t)h_Ns[0] * 4);
    float* y1      = (float*)alloc((size_t)h_Ns[0] * 4);
    float* xlr     = (float*)alloc((size_t)h_Ns[0] * 2048 * 4);
    float* gatout  = (float*)alloc((size_t)h_Ns[0] * 512 * 4);
    __bf16* Ah     = (__bf16*)alloc((size_t)h_Ns[0] * 512 * 2);
    __bf16* Al     = (__bf16*)alloc((size_t)h_Ns[0] * 512 * 2);
    __bf16* WtH    = (__bf16*)alloc((size_t)8 * 1024 * 512 * 2);
    __bf16* WtL    = (__bf16*)alloc((size_t)8 * 1024 * 512 * 2);
    float* biasC   = (float*)alloc((size_t)4 * 2048 * 4);
    float* W1t     = (float*)alloc((size_t)512 * 1024 * 4);
    float* W2t     = (float*)alloc((size_t)256 * 512 * 4);
    float* h1b     = (float*)alloc((size_t)NB * 512 * 4);
    float* h2b     = (float*)alloc((size_t)NB * 256 * 4);

    hipMemsetAsync(cnt, 0, (size_t)(h_Ns[0] + 1) * 4, stream);
    k_cvtWt<<<dim3(32, 16, 8), dim3(32, 8), 0, stream>>>(gWl, gWr, WtH, WtL);
    k_cvtA<<<(h_Ns[0] * 512 / 8 + 255) / 256, 256, 0, stream>>>(x0, Ah, Al, h_Ns[0] * 512);
    k_prep_bias<<<(4 * 2048 + 255) / 256, 256, 0, stream>>>(gbl, gbr, biasC);
    k_transpose<<<dim3(16, 32), dim3(32, 8), 0, stream>>>(W1, W1t, 1024, 512);
    k_transpose<<<dim3(8, 16), dim3(32, 8), 0, stream>>>(W2, W2t, 512, 256);

    for (int i = 0; i < 4; ++i) {
        int N = h_Ns[i], ng = h_ngs[i], k = h_ks[i];
        // bucket-CSR build (remap fused; cnt zeroed by memset / previous pool_readout)
        if (i == 0)
            k_init_build<<<(ETOT + 255) / 256, 256, 0, stream>>>(ei, s_src, s_dst, s_mask, cnt, bucket);
        else
            k_remap_build<<<(ETOT + 255) / 256, 256, 0, stream>>>(s_src, s_dst, s_mask, newidx, cnt, bucket);
        // combined xl|xr GEMM (bf16x3 MFMA, R6 structure)
        int nRows = (N + 127) >> 7;
        k_gemm3<<<nRows * 16, 256, 0, stream>>>(Ah, Al, WtH + (size_t)(2 * i) * 1024 * 512, WtL + (size_t)(2 * i) * 1024 * 512,
                                                biasC + (size_t)i * 2048, xlr, N, 2048);
        // fused GAT (wave per node, 2-edge unroll) + SAG row-dot epilogue
        k_gat_wave<<<(N + 3) / 4, 256, 0, stream>>>(xlr, cnt, bucket, gatt + (size_t)i * 1024,
                                                    gbias + (size_t)i * 512, sWrel + (size_t)i * 512,
                                                    sWroot + (size_t)i * 512, gatout, y0, y1, N);
        // fused score + top-k per graph
        k_topk_score<<<NB, 256, 0, stream>>>(y0, y1, cnt, bucket, sbrel + i, ng, k, newidx, sel_old, sel_scale);
        // fused pool (bf16 split, cnt zero) + readout partials into layer-i slice
        k_pool_readout<<<(NB * k) / 2 + 64, 256, 0, stream>>>(gatout, sel_old, sel_scale, Ah, Al, cnt, k,
                                                              pmax + (size_t)i * NB * 8 * 512,
                                                              psum + (size_t)i * NB * 8 * 512);
    }
    // readout fold (all layers) + MLP head
    k_readout_fin_all<<<NB, 512, 0, stream>>>(pmax, psum, readout);
    k_mlp1<<<512, 256, 0, stream>>>(readout, W1t, b1, h1b);
    k_mlp2<<<256, 256, 0, stream>>>(h1b, W2t, b2, h2b);
    k_mlp3<<<1, 256, 0, stream>>>(h2b, W3, b3, out);
}

// Round 12
// 636.236 us; speedup vs baseline: 1.1248x; 1.1248x over previous
//
#include <hip/hip_runtime.h>
#include <math.h>

#define NB   4
#define NG0  2500
#define ETOT 100000
#define CH   512
#define NEGS 0.2f
#define BCAP 64   // bucket capacity per dst node (max in-degree ~25)

static const int h_Ns[5]  = {10000, 7000, 4900, 3432, 2404};
static const int h_ngs[4] = {2500, 1750, 1225, 858};
static const int h_ks[4]  = {1750, 1225, 858, 601};

typedef __bf16 bf16x8 __attribute__((ext_vector_type(8)));
typedef __bf16 bf16x4 __attribute__((ext_vector_type(4)));
typedef float  f32x4  __attribute__((ext_vector_type(4)));

#define GLOAD16(g, l)                                                              \
    __builtin_amdgcn_global_load_lds(                                              \
        (const __attribute__((address_space(1))) unsigned int*)(g),                \
        (__attribute__((address_space(3))) unsigned int*)(l), 16, 0, 0)

// ---------------- layer-0: edge init + bucket-CSR build ----------------
__global__ void k_init_build(const int* __restrict__ ei, int* src, int* dst, int* mask,
                             int* cnt, int* bucket) {
    int e = blockIdx.x * blockDim.x + threadIdx.x;
    if (e >= ETOT) return;
    int s = ei[e], d = ei[ETOT + e];
    src[e] = s; dst[e] = d; mask[e] = 1;
    int p = atomicAdd(&cnt[d], 1);
    if (p < BCAP) bucket[(d << 6) + p] = s;
}

// ---------------- layer>0: remap + bucket-CSR build fused ----------------
__global__ void k_remap_build(int* src, int* dst, int* mask, const int* __restrict__ newidx,
                              int* cnt, int* bucket) {
    int e = blockIdx.x * blockDim.x + threadIdx.x;
    if (e >= ETOT) return;
    if (!mask[e]) return;
    int ns = newidx[src[e]];
    int nd = newidx[dst[e]];
    if (ns >= 0 && nd >= 0) {
        src[e] = ns; dst[e] = nd;
        int p = atomicAdd(&cnt[nd], 1);
        if (p < BCAP) bucket[(nd << 6) + p] = ns;
    } else mask[e] = 0;
}

// ---------------- f32 -> bf16 hi/lo split (layer 0 only) ----------------
__global__ void k_cvtA(const float* __restrict__ x, __bf16* __restrict__ hi,
                       __bf16* __restrict__ lo, int n) {
    int i = (blockIdx.x * blockDim.x + threadIdx.x) * 8;
    if (i >= n) return;
    float4 a = *(const float4*)(x + i);
    float4 b = *(const float4*)(x + i + 4);
    float f[8] = {a.x, a.y, a.z, a.w, b.x, b.y, b.z, b.w};
    bf16x8 vh, vl;
#pragma unroll
    for (int j = 0; j < 8; ++j) {
        __bf16 h = (__bf16)f[j];
        vh[j] = h;
        vl[j] = (__bf16)(f[j] - (float)h);
    }
    *(bf16x8*)(hi + i) = vh;
    *(bf16x8*)(lo + i) = vl;
}

// ---------------- W transpose + split ----------------
__global__ void k_cvtWt(const float* __restrict__ gWl, const float* __restrict__ gWr,
                        __bf16* __restrict__ WtH, __bf16* __restrict__ WtL) {
    int m = blockIdx.z;
    const float* src = ((m & 1) ? gWr : gWl) + (size_t)(m >> 1) * 512 * 1024;
    __bf16* oh = WtH + (size_t)m * 1024 * 512;
    __bf16* ol = WtL + (size_t)m * 1024 * 512;
    int nb = blockIdx.x * 32, kb = blockIdx.y * 32;
    __shared__ float tile[32][33];
#pragma unroll
    for (int j = 0; j < 4; ++j) {
        int kk = threadIdx.y + j * 8;
        tile[kk][threadIdx.x] = src[(size_t)(kb + kk) * 1024 + nb + threadIdx.x];
    }
    __syncthreads();
#pragma unroll
    for (int j = 0; j < 4; ++j) {
        int nn = threadIdx.y + j * 8;
        float v = tile[threadIdx.x][nn];
        __bf16 h = (__bf16)v;
        __bf16 l = (__bf16)(v - (float)h);
        oh[(size_t)(nb + nn) * 512 + kb + threadIdx.x] = h;
        ol[(size_t)(nb + nn) * 512 + kb + threadIdx.x] = l;
    }
}

// ---------------- generic f32 transpose ----------------
__global__ void k_transpose(const float* __restrict__ src, float* __restrict__ dst, int R, int C) {
    __shared__ float tile[32][33];
    int rb = blockIdx.y * 32, cb = blockIdx.x * 32;
#pragma unroll
    for (int j = 0; j < 4; ++j) {
        int r = rb + threadIdx.y + j * 8;
        int c = cb + threadIdx.x;
        if (r < R && c < C) tile[threadIdx.y + j * 8][threadIdx.x] = src[(size_t)r * C + c];
    }
    __syncthreads();
#pragma unroll
    for (int j = 0; j < 4; ++j) {
        int c = cb + threadIdx.y + j * 8;
        int r = rb + threadIdx.x;
        if (r < R && c < C) dst[(size_t)c * R + r] = tile[threadIdx.x][threadIdx.y + j * 8];
    }
}

// ---------------- combined bias [4][2048] = [bl | br] ----------------
__global__ void k_prep_bias(const float* __restrict__ gbl, const float* __restrict__ gbr,
                            float* __restrict__ biasC) {
    int i = blockIdx.x * blockDim.x + threadIdx.x;
    if (i >= 4 * 2048) return;
    int l = i >> 11, c = i & 2047;
    biasC[i] = (c < 1024) ? gbl[l * 1024 + c] : gbr[l * 1024 + c - 1024];
}

// ---------------- bf16x3 MFMA GEMM (R6 best-measured variant) ----------------
__global__ __launch_bounds__(256) void k_gemm3(const __bf16* __restrict__ Ah, const __bf16* __restrict__ Al,
                                               const __bf16* __restrict__ Bh, const __bf16* __restrict__ Bl,
                                               const float* __restrict__ bias, float* __restrict__ out,
                                               int M, int ldo) {
    __shared__ __bf16 sAh[128 * 32];
    __shared__ __bf16 sAl[128 * 32];
    __shared__ __bf16 sBh[128 * 32];
    __shared__ __bf16 sBl[128 * 32];
    int tid = threadIdx.x;
    int nRows = (M + 127) >> 7;
    int pid = blockIdx.x;
    int fullG = nRows >> 3;
    int inFull = fullG << 7;
    int rowT, colT;
    if (pid < inFull) {
        int g = pid >> 7, r = pid & 127;
        rowT = (g << 3) + (r & 7);
        colT = r >> 3;
    } else {
        int r = pid - inFull;
        int tail = nRows - (fullG << 3);
        rowT = (fullG << 3) + r % tail;
        colT = r / tail;
    }
    int rowBase = rowT << 7, colBase = colT << 7;
    int wave = tid >> 6, lane = tid & 63;
    int wr = (wave >> 1) * 64, wc = (wave & 1) * 64;
    f32x4 acc[4][4];
#pragma unroll
    for (int a = 0; a < 4; ++a)
#pragma unroll
        for (int b = 0; b < 4; ++b) { acc[a][b][0] = 0.f; acc[a][b][1] = 0.f; acc[a][b][2] = 0.f; acc[a][b][3] = 0.f; }

    int srow0 = tid >> 2;
    int ps = tid & 3;
    auto stage = [&](int k0) {
#pragma unroll
        for (int c = 0; c < 2; ++c) {
            int row = (c << 6) + srow0;
            int ls = ps ^ ((row >> 1) & 3);
            int ldsoff = c * 2048 + tid * 8;
            int grA = rowBase + row; if (grA >= M) grA = M - 1;
            int gnB = colBase + row;
            const __bf16* gah = Ah + (size_t)grA * 512 + k0 + ls * 8;
            const __bf16* gal = Al + (size_t)grA * 512 + k0 + ls * 8;
            const __bf16* gbh = Bh + (size_t)gnB * 512 + k0 + ls * 8;
            const __bf16* gbl2 = Bl + (size_t)gnB * 512 + k0 + ls * 8;
            GLOAD16(gah, &sAh[ldsoff]);
            GLOAD16(gal, &sAl[ldsoff]);
            GLOAD16(gbh, &sBh[ldsoff]);
            GLOAD16(gbl2, &sBl[ldsoff]);
        }
    };

    int fl = lane & 15, g = lane >> 4;
    stage(0);
    __syncthreads();
    for (int ks = 0; ks < 16; ++ks) {
        bf16x8 afh[4], afl[4], bfh[4], bfl[4];
#pragma unroll
        for (int fr = 0; fr < 4; ++fr) {
            int r = wr + fr * 16 + fl;
            int po = (g ^ ((r >> 1) & 3)) << 3;
            afh[fr] = *(const bf16x8*)&sAh[r * 32 + po];
            afl[fr] = *(const bf16x8*)&sAl[r * 32 + po];
        }
#pragma unroll
        for (int fc = 0; fc < 4; ++fc) {
            int cc = wc + fc * 16 + fl;
            int po = (g ^ ((cc >> 1) & 3)) << 3;
            bfh[fc] = *(const bf16x8*)&sBh[cc * 32 + po];
            bfl[fc] = *(const bf16x8*)&sBl[cc * 32 + po];
        }
        __syncthreads();
        if (ks < 15) stage((ks + 1) * 32);
#pragma unroll
        for (int fr = 0; fr < 4; ++fr) {
#pragma unroll
            for (int fc = 0; fc < 4; ++fc) {
                acc[fr][fc] = __builtin_amdgcn_mfma_f32_16x16x32_bf16(afh[fr], bfh[fc], acc[fr][fc], 0, 0, 0);
                acc[fr][fc] = __builtin_amdgcn_mfma_f32_16x16x32_bf16(afh[fr], bfl[fc], acc[fr][fc], 0, 0, 0);
                acc[fr][fc] = __builtin_amdgcn_mfma_f32_16x16x32_bf16(afl[fr], bfh[fc], acc[fr][fc], 0, 0, 0);
            }
        }
        __syncthreads();
    }
    int orow0 = rowBase + wr + 4 * (lane >> 4);
    int ocol0 = colBase + wc + fl;
#pragma unroll
    for (int fr = 0; fr < 4; ++fr) {
#pragma unroll
        for (int fc = 0; fc < 4; ++fc) {
            int col = ocol0 + fc * 16;
            float bv = bias[col];
#pragma unroll
            for (int j = 0; j < 4; ++j) {
                int row = orow0 + fr * 16 + j;
                if (row < M) out[(size_t)row * ldo + col] = acc[fr][fc][j] + bv;
            }
        }
    }
}

// ---------------- per-row logit + row load helper ----------------
__device__ __forceinline__ float gat_row(const float* __restrict__ xsp,
                                         const float* xr, const float* at, float* v) {
    float p = 0.f;
#pragma unroll
    for (int j = 0; j < 16; j += 4) {
        float4 vv = *(const float4*)(xsp + j);
        v[j + 0] = vv.x; v[j + 1] = vv.y; v[j + 2] = vv.z; v[j + 3] = vv.w;
    }
#pragma unroll
    for (int j = 0; j < 16; ++j) {
        float e = v[j] + xr[j];
        e = e > 0.f ? e : NEGS * e;
        p += e * at[j];
    }
    return p;
}

// ---------------- fused GAT: wave per dst node, 2-edge unrolled online softmax ----------------
__global__ __launch_bounds__(256) void k_gat_wave(const float* __restrict__ xlr,
                                                  const int* __restrict__ cnt,
                                                  const int* __restrict__ bucket,
                                                  const float* __restrict__ att,
                                                  const float* __restrict__ bias,
                                                  const float* __restrict__ Wrel,
                                                  const float* __restrict__ Wroot,
                                                  float* __restrict__ out,
                                                  float* __restrict__ y0, float* __restrict__ y1, int N) {
    int d = (blockIdx.x * blockDim.x + threadIdx.x) >> 6;
    if (d >= N) return;
    int lane = threadIdx.x & 63;
    int c0 = lane * 16;
    float xr[16], at[16];
#pragma unroll
    for (int j = 0; j < 16; j += 4) {
        float4 a = *(const float4*)(xlr + (size_t)d * 2048 + 1024 + c0 + j);
        xr[j + 0] = a.x; xr[j + 1] = a.y; xr[j + 2] = a.z; xr[j + 3] = a.w;
        float4 b = *(const float4*)(att + c0 + j);
        at[j + 0] = b.x; at[j + 1] = b.y; at[j + 2] = b.z; at[j + 3] = b.w;
    }
    float acc[16], m, den;
    {
        float v[16];
        float p = gat_row(xlr + (size_t)d * 2048 + c0, xr, at, v);
#pragma unroll
        for (int o = 1; o <= 16; o <<= 1) p += __shfl_xor(p, o, 64);
        m = p; den = 1.f;
#pragma unroll
        for (int j = 0; j < 16; ++j) acc[j] = v[j];
    }
    int rs = d << 6;
    int re = rs + cnt[d];
    int e = rs;
    for (; e + 1 < re; e += 2) {
        int s1 = bucket[e], s2 = bucket[e + 1];
        float v1[16], v2[16];
        float p1 = gat_row(xlr + (size_t)s1 * 2048 + c0, xr, at, v1);
        float p2 = gat_row(xlr + (size_t)s2 * 2048 + c0, xr, at, v2);
#pragma unroll
        for (int o = 1; o <= 16; o <<= 1) {
            p1 += __shfl_xor(p1, o, 64);
            p2 += __shfl_xor(p2, o, 64);
        }
        float nm = fmaxf(m, fmaxf(p1, p2));
        float sc = __expf(m - nm);
        float w1 = __expf(p1 - nm);
        float w2 = __expf(p2 - nm);
        m = nm;
        den = den * sc + w1 + w2;
#pragma unroll
        for (int j = 0; j < 16; ++j) acc[j] = (acc[j] * sc + w1 * v1[j]) + w2 * v2[j];
    }
    if (e < re) {
        int s1 = bucket[e];
        float v1[16];
        float p1 = gat_row(xlr + (size_t)s1 * 2048 + c0, xr, at, v1);
#pragma unroll
        for (int o = 1; o <= 16; o <<= 1) p1 += __shfl_xor(p1, o, 64);
        float nm = fmaxf(m, p1);
        float sc = __expf(m - nm);
        float w1 = __expf(p1 - nm);
        m = nm;
        den = den * sc + w1;
#pragma unroll
        for (int j = 0; j < 16; ++j) acc[j] = acc[j] * sc + w1 * v1[j];
    }
    float inv = 1.f / fmaxf(den, 1e-16f);
    float o16[16];
#pragma unroll
    for (int j = 0; j < 16; ++j) {
        float a = acc[j] * inv;
        float b = __shfl_xor(a, 32, 64);
        o16[j] = 0.5f * (a + b);
    }
    float s0 = 0.f, s1v = 0.f;
    if (lane < 32) {
        const float* bp = bias + c0;
        const float* wa = Wrel + c0;
        const float* wb = Wroot + c0;
        float* op = out + (size_t)d * 512 + c0;
#pragma unroll
        for (int j = 0; j < 16; j += 4) {
            float4 bb = *(const float4*)(bp + j);
            float4 va = *(const float4*)(wa + j);
            float4 vb = *(const float4*)(wb + j);
            float4 r;
            r.x = fmaxf(o16[j + 0] + bb.x, 0.f);
            r.y = fmaxf(o16[j + 1] + bb.y, 0.f);
            r.z = fmaxf(o16[j + 2] + bb.z, 0.f);
            r.w = fmaxf(o16[j + 3] + bb.w, 0.f);
            *(float4*)(op + j) = r;
            s0 += r.x * va.x + r.y * va.y + r.z * va.z + r.w * va.w;
            s1v += r.x * vb.x + r.y * vb.y + r.z * vb.z + r.w * vb.w;
        }
    }
#pragma unroll
    for (int o = 16; o > 0; o >>= 1) {
        s0 += __shfl_xor(s0, o, 64);
        s1v += __shfl_xor(s1v, o, 64);
    }
    s0 += __shfl_xor(s0, 32, 64);
    s1v += __shfl_xor(s1v, 32, 64);
    if (lane == 0) { y0[d] = s0; y1[d] = s1v; }
}

// ---------------- score via bucket scalar sums (1 thread / node) ----------------
__global__ void k_score2(const float* __restrict__ y0, const float* __restrict__ y1,
                         const int* __restrict__ cnt, const int* __restrict__ bucket,
                         const float* __restrict__ brel_p,
                         float* __restrict__ score, int N) {
    int d = blockIdx.x * blockDim.x + threadIdx.x;
    if (d >= N) return;
    float s = y1[d] + brel_p[0];
    int rs = d << 6, re = rs + cnt[d];
    for (int e = rs; e < re; ++e) s += y0[bucket[e]];
    score[d] = s;
}

// ---------------- per-graph top-k via radix select (parallel digit select) ----------------
__global__ __launch_bounds__(256) void k_topk_radix(const float* __restrict__ score, int ng, int k,
                                                    int* __restrict__ newidx, int* __restrict__ sel_old,
                                                    float* __restrict__ sel_scale) {
    int b = blockIdx.x;
    int t = threadIdx.x;
    int lane = t & 63, wave = t >> 6;
    __shared__ unsigned int keys[NG0];
    __shared__ int hist[256];
    __shared__ int scnt[256];
    __shared__ int wsum4[4];
    __shared__ unsigned int s_pref, s_amask;
    __shared__ int s_krem, s_gt;
    for (int i = t; i < ng; i += 256) {
        float f = score[b * ng + i];
        unsigned int u = __float_as_uint(f);
        u = (u & 0x80000000u) ? ~u : (u | 0x80000000u);
        keys[i] = u;
        newidx[b * ng + i] = -1;
    }
    if (t == 0) { s_pref = 0u; s_amask = 0u; s_krem = k; s_gt = 0; }
    __syncthreads();
    for (int pass = 0; pass < 4; ++pass) {
        int shift = 24 - 8 * pass;
        hist[t] = 0;
        __syncthreads();
        unsigned int amask = s_amask, pref = s_pref;
        int krem_c = s_krem;
        for (int i = t; i < ng; i += 256) {
            unsigned int u = keys[i];
            if ((u & amask) == pref) atomicAdd(&hist[(u >> shift) & 255], 1);
        }
        __syncthreads();
        int rh = hist[255 - t];
        int x = rh;
#pragma unroll
        for (int o = 1; o < 64; o <<= 1) {
            int y = __shfl_up(x, o, 64);
            if (lane >= o) x += y;
        }
        if (lane == 63) wsum4[wave] = x;
        __syncthreads();
        int woff = 0;
#pragma unroll
        for (int wv = 0; wv < 3; ++wv) if (wave > wv) woff += wsum4[wv];
        x += woff;
        if (x >= krem_c && (x - rh) < krem_c) {
            s_pref = pref | ((unsigned int)(255 - t) << shift);
            s_amask = amask | (0xFFu << shift);
            s_krem = krem_c - (x - rh);
        }
        __syncthreads();
    }
    unsigned int T = s_pref;
    int krem = s_krem;
    int chunk = (ng + 255) / 256;
    int lo = t * chunk, hi = min(ng, lo + chunk);
    int ceq = 0;
    for (int i = lo; i < hi; ++i) if (keys[i] == T) ceq++;
    scnt[t] = ceq;
    __syncthreads();
    for (int o = 1; o < 256; o <<= 1) {
        int add = (t >= o) ? scnt[t - o] : 0;
        __syncthreads();
        scnt[t] += add;
        __syncthreads();
    }
    int eq_rank = scnt[t] - ceq;
    for (int i = lo; i < hi; ++i) {
        unsigned int u = keys[i];
        int slot = -1;
        if (u > T) slot = atomicAdd(&s_gt, 1);
        else if (u == T) {
            if (eq_rank < krem) slot = (k - krem) + eq_rank;
            eq_rank++;
        }
        if (slot >= 0) {
            int oldg = b * ng + i;
            int newg = b * k + slot;
            newidx[oldg] = newg;
            sel_old[newg] = oldg;
            sel_scale[newg] = tanhf(score[oldg]);
        }
    }
}

// ---------------- fused pool (bf16 split + cnt zero) & readout phase 1 ----------------
__global__ __launch_bounds__(256) void k_pool_readout(const float* __restrict__ gatout,
                                                      const int* __restrict__ sel_old,
                                                      const float* __restrict__ sel_scale,
                                                      __bf16* __restrict__ hi, __bf16* __restrict__ lo,
                                                      int* __restrict__ cnt, int k,
                                                      float* __restrict__ pmax, float* __restrict__ psum) {
    int npoolb = (NB * k) >> 1;
    int bid = blockIdx.x;
    if (bid < npoolb) {
        int nn = (bid << 1) + (threadIdx.x >> 7);
        int t2 = threadIdx.x & 127;
        if (t2 == 0) cnt[nn] = 0;
        int so = sel_old[nn];
        float sc = sel_scale[nn];
        int c = t2 * 4;
        float4 vv = *(const float4*)(gatout + (size_t)so * 512 + c);
        vv.x *= sc; vv.y *= sc; vv.z *= sc; vv.w *= sc;
        float f[4] = {vv.x, vv.y, vv.z, vv.w};
        bf16x4 vh, vl;
#pragma unroll
        for (int j = 0; j < 4; ++j) {
            __bf16 hh = (__bf16)f[j];
            vh[j] = hh;
            vl[j] = (__bf16)(f[j] - (float)hh);
        }
        *(bf16x4*)(hi + (size_t)nn * 512 + c) = vh;
        *(bf16x4*)(lo + (size_t)nn * 512 + c) = vl;
        return;
    }
    int rb = bid - npoolb;          // 0..63
    int b = rb >> 4;
    int cg = (rb >> 3) & 1;
    int rc = rb & 7;
    int t = threadIdx.x;
    int c4 = t & 63;
    int rl = t >> 6;
    int col = cg * 256 + c4 * 4;
    int rstart = rc * 4 + rl;
    float4 mx = make_float4(-1e30f, -1e30f, -1e30f, -1e30f);
    float4 sm = make_float4(0.f, 0.f, 0.f, 0.f);
    for (int j = rstart; j < k; j += 32) {
        int so = sel_old[b * k + j];
        float sc = sel_scale[b * k + j];
        float4 v = *(const float4*)(gatout + (size_t)so * 512 + col);
        v.x *= sc; v.y *= sc; v.z *= sc; v.w *= sc;
        mx.x = fmaxf(mx.x, v.x); mx.y = fmaxf(mx.y, v.y); mx.z = fmaxf(mx.z, v.z); mx.w = fmaxf(mx.w, v.w);
        sm.x += v.x; sm.y += v.y; sm.z += v.z; sm.w += v.w;
    }
    __shared__ float lmx[256 * 4];
    __shared__ float lsm[256 * 4];
    int li = c4 * 4 + rl * 256;
    lmx[li + 0] = mx.x; lmx[li + 1] = mx.y; lmx[li + 2] = mx.z; lmx[li + 3] = mx.w;
    lsm[li + 0] = sm.x; lsm[li + 1] = sm.y; lsm[li + 2] = sm.z; lsm[li + 3] = sm.w;
    __syncthreads();
    if (rl == 0) {
        int ci = c4 * 4;
#pragma unroll
        for (int q = 0; q < 4; ++q) {
            float m = fmaxf(fmaxf(lmx[ci + q], lmx[ci + q + 256]), fmaxf(lmx[ci + q + 512], lmx[ci + q + 768]));
            float s = lsm[ci + q] + lsm[ci + q + 256] + lsm[ci + q + 512] + lsm[ci + q + 768];
            size_t o = ((size_t)(b * 8 + rc)) * 512 + col + q;
            pmax[o] = m;
            psum[o] = s;
        }
    }
}

// ---------------- readout final: fold 4 layers x 8 chunks once ----------------
__global__ __launch_bounds__(512) void k_readout_fin_all(const float* __restrict__ pmax,
                                                         const float* __restrict__ psum,
                                                         float* __restrict__ readout) {
    const int ks[4] = {1750, 1225, 858, 601};
    int b = blockIdx.x;
    int c = threadIdx.x;
    float accm = 0.f, accs = 0.f;
#pragma unroll
    for (int L = 0; L < 4; ++L) {
        float m = -1e30f, s = 0.f;
#pragma unroll
        for (int rc = 0; rc < 8; ++rc) {
            size_t o = ((size_t)(L * NB * 8) + b * 8 + rc) * 512 + c;
            m = fmaxf(m, pmax[o]);
            s += psum[o];
        }
        accm += m;
        accs += s / (float)ks[L];
    }
    readout[b * 1024 + c] = accm;
    readout[b * 1024 + 512 + c] = accs;
}

// ---------------- MLP stages ----------------
__global__ __launch_bounds__(256) void k_mlp1(const float* __restrict__ readout, const float* __restrict__ W1t,
                                              const float* __restrict__ b1, float* __restrict__ h1) {
    int wid = (blockIdx.x * blockDim.x + threadIdx.x) >> 6;
    int lane = threadIdx.x & 63;
    int b = wid >> 9, col = wid & 511;
    const float* rp = readout + b * 1024 + lane * 16;
    const float* wp = W1t + (size_t)col * 1024 + lane * 16;
    float s = 0.f;
#pragma unroll
    for (int j = 0; j < 4; ++j) {
        float4 v = *(const float4*)(rp + j * 4);
        float4 w = *(const float4*)(wp + j * 4);
        s += v.x * w.x + v.y * w.y + v.z * w.z + v.w * w.w;
    }
#pragma unroll
    for (int o = 32; o > 0; o >>= 1) s += __shfl_xor(s, o, 64);
    if (lane == 0) h1[b * 512 + col] = fmaxf(s + b1[col], 0.f);
}

__global__ __launch_bounds__(256) void k_mlp2(const float* __restrict__ h1, const float* __restrict__ W2t,
                                              const float* __restrict__ b2, float* __restrict__ h2) {
    int wid = (blockIdx.x * blockDim.x + threadIdx.x) >> 6;
    int lane = threadIdx.x & 63;
    int b = wid >> 8, col = wid & 255;
    const float* hp = h1 + b * 512 + lane * 8;
    const float* wp = W2t + (size_t)col * 512 + lane * 8;
    float s = 0.f;
#pragma unroll
    for (int j = 0; j < 2; ++j) {
        float4 v = *(const float4*)(hp + j * 4);
        float4 w = *(const float4*)(wp + j * 4);
        s += v.x * w.x + v.y * w.y + v.z * w.z + v.w * w.w;
    }
#pragma unroll
    for (int o = 32; o > 0; o >>= 1) s += __shfl_xor(s, o, 64);
    if (lane == 0) h2[b * 256 + col] = fmaxf(s + b2[col], 0.f);
}

__global__ __launch_bounds__(256) void k_mlp3(const float* __restrict__ h2, const float* __restrict__ W3,
                                              const float* __restrict__ b3, float* __restrict__ out) {
    int b = threadIdx.x >> 6;
    int lane = threadIdx.x & 63;
    float hv[4];
    int idx[4];
#pragma unroll
    for (int j = 0; j < 4; ++j) { idx[j] = lane + j * 64; hv[j] = h2[b * 256 + idx[j]]; }
    float lg[5];
#pragma unroll
    for (int q = 0; q < 5; ++q) {
        float p = 0.f;
#pragma unroll
        for (int j = 0; j < 4; ++j) p += hv[j] * W3[idx[j] * 5 + q];
#pragma unroll
        for (int o = 32; o > 0; o >>= 1) p += __shfl_xor(p, o, 64);
        lg[q] = p + b3[q];
    }
    if (lane == 0) {
        float m = lg[0];
#pragma unroll
        for (int q = 1; q < 5; ++q) m = fmaxf(m, lg[q]);
        float den = 0.f;
#pragma unroll
        for (int q = 0; q < 5; ++q) den += __expf(lg[q] - m);
#pragma unroll
        for (int q = 0; q < 5; ++q) {
            out[b * 5 + q] = lg[q];
            out[NB * 5 + b * 5 + q] = __expf(lg[q] - m) / den;
        }
    }
}

extern "C" void kernel_launch(void* const* d_in, const int* in_sizes, int n_in,
                              void* d_out, int out_size, void* d_ws, size_t ws_size,
                              hipStream_t stream) {
    const float* x0    = (const float*)d_in[0];
    const int*   ei    = (const int*)d_in[1];
    const float* gWl   = (const float*)d_in[2];
    const float* gbl   = (const float*)d_in[3];
    const float* gWr   = (const float*)d_in[4];
    const float* gbr   = (const float*)d_in[5];
    const float* gatt  = (const float*)d_in[6];
    const float* gbias = (const float*)d_in[7];
    const float* sWrel = (const float*)d_in[8];
    const float* sbrel = (const float*)d_in[9];
    const float* sWroot= (const float*)d_in[10];
    const float* W1 = (const float*)d_in[11];
    const float* b1 = (const float*)d_in[12];
    const float* W2 = (const float*)d_in[13];
    const float* b2 = (const float*)d_in[14];
    const float* W3 = (const float*)d_in[15];
    const float* b3 = (const float*)d_in[16];
    float* out = (float*)d_out;

    char* base = (char*)d_ws;
    size_t off = 0;
    auto alloc = [&](size_t bytes) -> void* {
        void* p = base + off;
        off += (bytes + 255) & ~(size_t)255;
        return p;
    };
    int*   s_src   = (int*)alloc((size_t)ETOT * 4);
    int*   s_dst   = (int*)alloc((size_t)ETOT * 4);
    int*   s_mask  = (int*)alloc((size_t)ETOT * 4);
    int*   bucket  = (int*)alloc((size_t)h_Ns[0] * BCAP * 4);
    int*   cnt     = (int*)alloc((size_t)(h_Ns[0] + 1) * 4);
    float* score   = (float*)alloc((size_t)h_Ns[0] * 4);
    int*   newidx  = (int*)alloc((size_t)h_Ns[0] * 4);
    int*   sel_old = (int*)alloc((size_t)7000 * 4);
    float* sel_scale = (float*)alloc((size_t)7000 * 4);
    float* readout = (float*)alloc((size_t)NB * 1024 * 4);
    float* pmax    = (float*)alloc((size_t)4 * NB * 8 * 512 * 4);
    float* psum    = (float*)alloc((size_t)4 * NB * 8 * 512 * 4);
    float* y0      = (float*)alloc((size_t)h_Ns[0] * 4);
    float* y1      = (float*)alloc((size_t)h_Ns[0] * 4);
    float* xlr     = (float*)alloc((size_t)h_Ns[0] * 2048 * 4);
    float* gatout  = (float*)alloc((size_t)h_Ns[0] * 512 * 4);
    __bf16* Ah     = (__bf16*)alloc((size_t)h_Ns[0] * 512 * 2);
    __bf16* Al     = (__bf16*)alloc((size_t)h_Ns[0] * 512 * 2);
    __bf16* WtH    = (__bf16*)alloc((size_t)8 * 1024 * 512 * 2);
    __bf16* WtL    = (__bf16*)alloc((size_t)8 * 1024 * 512 * 2);
    float* biasC   = (float*)alloc((size_t)4 * 2048 * 4);
    float* W1t     = (float*)alloc((size_t)512 * 1024 * 4);
    float* W2t     = (float*)alloc((size_t)256 * 512 * 4);
    float* h1b     = (float*)alloc((size_t)NB * 512 * 4);
    float* h2b     = (float*)alloc((size_t)NB * 256 * 4);

    hipMemsetAsync(cnt, 0, (size_t)(h_Ns[0] + 1) * 4, stream);
    k_cvtWt<<<dim3(32, 16, 8), dim3(32, 8), 0, stream>>>(gWl, gWr, WtH, WtL);
    k_cvtA<<<(h_Ns[0] * 512 / 8 + 255) / 256, 256, 0, stream>>>(x0, Ah, Al, h_Ns[0] * 512);
    k_prep_bias<<<(4 * 2048 + 255) / 256, 256, 0, stream>>>(gbl, gbr, biasC);
    k_transpose<<<dim3(16, 32), dim3(32, 8), 0, stream>>>(W1, W1t, 1024, 512);
    k_transpose<<<dim3(8, 16), dim3(32, 8), 0, stream>>>(W2, W2t, 512, 256);

    for (int i = 0; i < 4; ++i) {
        int N = h_Ns[i], ng = h_ngs[i], k = h_ks[i];
        // bucket-CSR build (remap fused; cnt zeroed by memset / previous pool_readout)
        if (i == 0)
            k_init_build<<<(ETOT + 255) / 256, 256, 0, stream>>>(ei, s_src, s_dst, s_mask, cnt, bucket);
        else
            k_remap_build<<<(ETOT + 255) / 256, 256, 0, stream>>>(s_src, s_dst, s_mask, newidx, cnt, bucket);
        // combined xl|xr GEMM (bf16x3 MFMA, R6 structure)
        int nRows = (N + 127) >> 7;
        k_gemm3<<<nRows * 16, 256, 0, stream>>>(Ah, Al, WtH + (size_t)(2 * i) * 1024 * 512, WtL + (size_t)(2 * i) * 1024 * 512,
                                                biasC + (size_t)i * 2048, xlr, N, 2048);
        // fused GAT (wave per node, 2-edge unroll) + SAG row-dot epilogue
        k_gat_wave<<<(N + 3) / 4, 256, 0, stream>>>(xlr, cnt, bucket, gatt + (size_t)i * 1024,
                                                    gbias + (size_t)i * 512, sWrel + (size_t)i * 512,
                                                    sWroot + (size_t)i * 512, gatout, y0, y1, N);
        // score (1 thread/node, massively parallel)
        k_score2<<<(N + 255) / 256, 256, 0, stream>>>(y0, y1, cnt, bucket, sbrel + i, score, N);
        // top-k per graph
        k_topk_radix<<<NB, 256, 0, stream>>>(score, ng, k, newidx, sel_old, sel_scale);
        // fused pool (bf16 split, cnt zero) + readout partials into layer-i slice
        k_pool_readout<<<(NB * k) / 2 + 64, 256, 0, stream>>>(gatout, sel_old, sel_scale, Ah, Al, cnt, k,
                                                              pmax + (size_t)i * NB * 8 * 512,
                                                              psum + (size_t)i * NB * 8 * 512);
    }
    // readout fold (all layers) + MLP head
    k_readout_fin_all<<<NB, 512, 0, stream>>>(pmax, psum, readout);
    k_mlp1<<<512, 256, 0, stream>>>(readout, W1t, b1, h1b);
    k_mlp2<<<256, 256, 0, stream>>>(h1b, W2t, b2, h2b);
    k_mlp3<<<1, 256, 0, stream>>>(h2b, W3, b3, out);
}